// Round 2
// baseline (26383.011 us; speedup 1.0000x reference)
//
#include <hip/hip_runtime.h>

typedef unsigned short u16;
typedef short bf16x8 __attribute__((ext_vector_type(8)));
typedef float f32x4 __attribute__((ext_vector_type(4)));
typedef u16 u16x8 __attribute__((ext_vector_type(8)));

#define LDA_EFF 6144
#define BD (256 * 1024)
#define NBLK 256

__device__ inline u16 f2bf(float f) {
  unsigned u = __float_as_uint(f);
  unsigned r = (u + 0x7fffu + ((u >> 16) & 1u)) >> 16;
  return (u16)r;
}
__device__ inline float bf2f(u16 h) { return __uint_as_float(((unsigned)h) << 16); }

__device__ inline void gload_lds16(const u16* g, u16* l) {
  __builtin_amdgcn_global_load_lds(
      (const __attribute__((address_space(1))) void*)g,
      (__attribute__((address_space(3))) void*)l, 16, 0, 0);
}

// Device-wide sense-reversing barrier. bar[0]=arrive counter, bar[1]=generation.
// All NBLK blocks co-resident (1 block/CU), so spinning is safe.
__device__ __forceinline__ void grid_barrier(unsigned* bar) {
  __syncthreads();
  if (threadIdx.x == 0) {
    __threadfence();  // make this block's writes visible at agent scope
    unsigned g = __hip_atomic_load(&bar[1], __ATOMIC_RELAXED, __HIP_MEMORY_SCOPE_AGENT);
    unsigned old = __hip_atomic_fetch_add(&bar[0], 1u, __ATOMIC_ACQ_REL, __HIP_MEMORY_SCOPE_AGENT);
    if (old == NBLK - 1) {
      __hip_atomic_store(&bar[0], 0u, __ATOMIC_RELAXED, __HIP_MEMORY_SCOPE_AGENT);
      __hip_atomic_store(&bar[1], g + 1u, __ATOMIC_RELEASE, __HIP_MEMORY_SCOPE_AGENT);
    } else {
      while (__hip_atomic_load(&bar[1], __ATOMIC_ACQUIRE, __HIP_MEMORY_SCOPE_AGENT) == g) {}
    }
    __threadfence();
  }
  __syncthreads();
}

// C[m][n] = sum_k A[m][k] * B[n][k]  (bf16 in, f32 partial out per K-split)
// BM=128, BN=64, BK=32, 256 threads, 4 waves as 2x2 (wave tile 64x32).
// 4-buffer depth-2 prefetch via global_load_lds, counted vmcnt, raw s_barrier.
template <int NT, int MB, int NB>
__device__ __forceinline__ void gemm_phase(
    const u16* __restrict__ A, const u16* __restrict__ B,
    float* __restrict__ C, int lda, int ldb, u16* Ts, int bid, int tid) {
  constexpr int BM = 128, BN = 64, BK = 32;
  constexpr int N = NB * BN;
  constexpr int KS = NT * BK;
  constexpr int TSZ = (BM + BN) * BK;

  const int mb = bid % MB;
  const int nb = (bid / MB) % NB;
  const int kb = bid / (MB * NB);

  const u16* Ab = A + (mb * BM) * lda + kb * KS;
  const u16* Bb = B + (nb * BN) * ldb + kb * KS;

  const int lane = tid & 63;
  const int wid = tid >> 6;
  const int wrow = (wid >> 1) * 64;
  const int wcol = (wid & 1) * 32;
  const int lr = lane & 15;
  const int lk = (lane >> 4) * 8;

  f32x4 acc[4][2];
#pragma unroll
  for (int m = 0; m < 4; m++)
#pragma unroll
    for (int n = 0; n < 2; n++) acc[m][n] = (f32x4)0.f;

  auto STAGE = [&](int buf, int kt) {
    const int base = kt * BK;
#pragma unroll
    for (int r = 0; r < (BM + BN) / 64; r++) {
      int f16 = r * 256 + tid;  // 16-byte unit index, linear in LDS
      const u16* g;
      if (f16 < BM * 4) {
        g = Ab + (f16 >> 2) * lda + base + (f16 & 3) * 8;
      } else {
        int f2 = f16 - BM * 4;
        g = Bb + (f2 >> 2) * ldb + base + (f2 & 3) * 8;
      }
      gload_lds16(g, &Ts[buf * TSZ + f16 * 8]);
    }
  };

  auto COMPUTE = [&](int cur) {
    const u16* Abuf = &Ts[cur * TSZ];
    const u16* Bbuf = &Ts[cur * TSZ + BM * BK];
    bf16x8 af[4], bfr[2];
#pragma unroll
    for (int m = 0; m < 4; m++)
      af[m] = *(const bf16x8*)&Abuf[(wrow + m * 16 + lr) * BK + lk];
#pragma unroll
    for (int n = 0; n < 2; n++)
      bfr[n] = *(const bf16x8*)&Bbuf[(wcol + n * 16 + lr) * BK + lk];
#pragma unroll
    for (int m = 0; m < 4; m++)
#pragma unroll
      for (int n = 0; n < 2; n++)
        acc[m][n] = __builtin_amdgcn_mfma_f32_16x16x32_bf16(af[m], bfr[n], acc[m][n], 0, 0, 0);
  };

  STAGE(0, 0);
  STAGE(1, 1);
  for (int t = 0; t < NT - 2; t++) {
    STAGE((t + 2) & 3, t + 2);
    asm volatile("s_waitcnt vmcnt(6)" ::: "memory");
    __builtin_amdgcn_s_barrier();
    COMPUTE(t & 3);
  }
  asm volatile("s_waitcnt vmcnt(3)" ::: "memory");
  __builtin_amdgcn_s_barrier();
  COMPUTE((NT - 2) & 3);
  asm volatile("s_waitcnt vmcnt(0)" ::: "memory");
  __builtin_amdgcn_s_barrier();
  COMPUTE((NT - 1) & 3);

  // Epilogue: f32 partial store. C frag layout: col=lane&15, row=(lane>>4)*4+j.
  float* Cb = C + (size_t)kb * (256 * N) + (size_t)(mb * BM + wrow) * N + nb * BN + wcol;
#pragma unroll
  for (int m = 0; m < 4; m++)
#pragma unroll
    for (int n = 0; n < 2; n++)
#pragma unroll
      for (int j = 0; j < 4; j++) {
        int row = m * 16 + (lane >> 4) * 4 + j;
        int col = n * 16 + lr;
        Cb[row * N + col] = acc[m][n][j];
      }
  __builtin_amdgcn_s_barrier();  // protect LDS reuse before next phase's STAGE
}

// Persistent kernel: 256 blocks x 256 threads (1 block/CU). All 128 steps +
// final BatchNorm, with custom grid barriers between dependent phases.
__global__ __launch_bounds__(256) void fused_persistent(
    const float* __restrict__ b_ih, const float* __restrict__ b_hh,
    const float* __restrict__ b_lin,
    u16* __restrict__ Aeff, const u16* __restrict__ Beff,
    const u16* __restrict__ B2eff, float* __restrict__ cbuf,
    float* __restrict__ gates, float* __restrict__ ybuf,
    float* __restrict__ out, unsigned* __restrict__ bar) {
  __shared__ __attribute__((aligned(16))) u16 Ts[4 * (128 + 64) * 32];
  const int bid = blockIdx.x;
  const int tid = threadIdx.x;

  for (int t = 0; t < 128; t++) {
    // Phase A: gates partials. K=6144 split 2, N=4096. grid 2x64x2 = 256.
    gemm_phase<96, 2, 64>(Aeff, Beff, gates, 6144, 6144, Ts, bid, tid);
    grid_barrier(bar);

    // Phase B: cell update. 262144 elems / 256 blocks = 1024 per block.
    {
      const float* g0 = gates;
      const float* g1 = gates + 1048576;
#pragma unroll
      for (int i = 0; i < 4; i++) {
        int idx = (bid << 10) + (i << 8) + tid;
        int b = idx >> 10, n = idx & 1023;
        int gb = b * 4096 + n;
        float xi = g0[gb] + g1[gb] + b_ih[n] + b_hh[n];
        float xf = g0[gb + 1024] + g1[gb + 1024] + b_ih[n + 1024] + b_hh[n + 1024];
        float xg = g0[gb + 2048] + g1[gb + 2048] + b_ih[n + 2048] + b_hh[n + 2048];
        float xo = g0[gb + 3072] + g1[gb + 3072] + b_ih[n + 3072] + b_hh[n + 3072];
        float ig = 1.f / (1.f + expf(-xi));
        float fg = 1.f / (1.f + expf(-xf));
        float gg = tanhf(xg);
        float og = 1.f / (1.f + expf(-xo));
        float cn = fg * cbuf[idx] + ig * gg;
        float h = og * tanhf(cn);
        cbuf[idx] = cn;
        u16 hi = f2bf(h);
        u16 lo = f2bf(h - bf2f(hi));
        u16* ar = Aeff + b * LDA_EFF;
        ar[3072 + n] = hi;
        ar[4096 + n] = lo;
        ar[5120 + n] = hi;
      }
    }
    grid_barrier(bar);

    // Phase C: y partials. A = h-triple, K=3072 split 8, N=1024. grid 2x16x8.
    gemm_phase<12, 2, 16>(Aeff + 3072, B2eff, ybuf, 6144, 3072, Ts, bid, tid);
    grid_barrier(bar);

    // Phase D: y-finish -> out[t] and next x into Aeff.
    {
      float* out_t = out + (size_t)t * BD;
#pragma unroll
      for (int i = 0; i < 4; i++) {
        int idx = (bid << 10) + (i << 8) + tid;
        int b = idx >> 10, n = idx & 1023;
        float y = b_lin[n];
#pragma unroll
        for (int p = 0; p < 8; p++) y += ybuf[p * BD + idx];
        out_t[idx] = y;
        u16 hi = f2bf(y);
        u16 lo = f2bf(y - bf2f(hi));
        u16* ar = Aeff + b * LDA_EFF;
        ar[n] = hi;
        ar[1024 + n] = lo;
        ar[2048 + n] = hi;
      }
    }
    grid_barrier(bar);
  }

  // BatchNorm over batch axis: 128 t x 4 chunks = 512 units, 2 per block.
  for (int u = 0; u < 2; u++) {
    int unit = (bid << 1) + u;
    int tt = unit >> 2;
    int d = ((unit & 3) << 8) + tid;
    float* base = out + (size_t)tt * BD + d;
    float s = 0.f;
    for (int b = 0; b < 256; b++) s += base[b * 1024];
    float mean = s * (1.f / 256.f);
    float vs = 0.f;
    for (int b = 0; b < 256; b++) {
      float x = base[b * 1024] - mean;
      vs += x * x;
    }
    float rstd = rsqrtf(vs * (1.f / 256.f) + 1e-5f);
    for (int b = 0; b < 256; b++) base[b * 1024] = (base[b * 1024] - mean) * rstd;
  }
}

__global__ void init_bar(unsigned* bar) {
  bar[0] = 0;
  bar[1] = 0;
}

// Build B_eff (4096 x 6144): [Wih_hi|Wih_hi|Wih_lo|Whh_hi|Whh_hi|Whh_lo]
__global__ __launch_bounds__(256) void prep_w1(
    const float* __restrict__ Wih, const float* __restrict__ Whh,
    u16* __restrict__ Beff) {
  int i8 = blockIdx.x * 256 + threadIdx.x;  // 0..3145727 (8 elems each)
  int j = i8 / 768, r8 = i8 % 768;
  int sec = r8 >> 7, k8 = (r8 & 127) << 3;
  const float* src = ((sec < 3) ? Wih : Whh) + j * 1024 + k8;
  bool lo = (sec == 2 || sec == 5);
  u16x8 o;
#pragma unroll
  for (int e = 0; e < 8; e++) {
    float f = src[e];
    u16 hi = f2bf(f);
    o[e] = lo ? f2bf(f - bf2f(hi)) : hi;
  }
  *(u16x8*)&Beff[(size_t)i8 * 8] = o;
}

// Build B2_eff (1024 x 3072): [Wlin_hi|Wlin_hi|Wlin_lo]
__global__ __launch_bounds__(256) void prep_w2(
    const float* __restrict__ Wlin, u16* __restrict__ B2eff) {
  int i8 = blockIdx.x * 256 + threadIdx.x;  // 0..393215
  int j = i8 / 384, r8 = i8 % 384;
  int sec = r8 >> 7, k8 = (r8 & 127) << 3;
  const float* src = Wlin + j * 1024 + k8;
  bool lo = (sec == 2);
  u16x8 o;
#pragma unroll
  for (int e = 0; e < 8; e++) {
    float f = src[e];
    u16 hi = f2bf(f);
    o[e] = lo ? f2bf(f - bf2f(hi)) : hi;
  }
  *(u16x8*)&B2eff[(size_t)i8 * 8] = o;
}

// Init A_eff = [x_hi|x_lo|x_hi|h_hi|h_lo|h_hi] from inputs/h0, and c from c0.
__global__ __launch_bounds__(256) void prep_state(
    const float* __restrict__ x0, const float* __restrict__ h0,
    const float* __restrict__ c0, u16* __restrict__ Aeff, float* __restrict__ c) {
  int i8 = blockIdx.x * 256 + threadIdx.x;  // 0..196607
  int b = i8 / 768, r8 = i8 % 768;
  int sec = r8 >> 7, k8 = (r8 & 127) << 3;
  const float* src = ((sec < 3) ? x0 : h0) + b * 1024 + k8;
  bool lo = (sec == 1 || sec == 4);
  u16x8 o;
#pragma unroll
  for (int e = 0; e < 8; e++) {
    float f = src[e];
    u16 hi = f2bf(f);
    o[e] = lo ? f2bf(f - bf2f(hi)) : hi;
  }
  *(u16x8*)&Aeff[(size_t)i8 * 8] = o;
  if (i8 < 32768) {
    float4 v0 = *(const float4*)&c0[i8 * 8];
    float4 v1 = *(const float4*)&c0[i8 * 8 + 4];
    *(float4*)&c[i8 * 8] = v0;
    *(float4*)&c[i8 * 8 + 4] = v1;
  }
}

extern "C" void kernel_launch(void* const* d_in, const int* in_sizes, int n_in,
                              void* d_out, int out_size, void* d_ws, size_t ws_size,
                              hipStream_t stream) {
  const float* inputs = (const float*)d_in[0];
  const float* W_ih = (const float*)d_in[1];
  const float* W_hh = (const float*)d_in[2];
  const float* b_ih = (const float*)d_in[3];
  const float* b_hh = (const float*)d_in[4];
  const float* W_lin = (const float*)d_in[5];
  const float* b_lin = (const float*)d_in[6];
  const float* h0 = (const float*)d_in[7];
  const float* c0 = (const float*)d_in[8];
  float* out = (float*)d_out;

  char* ws = (char*)d_ws;
  unsigned* bar = (unsigned*)ws;                // 256 B (2 used)
  u16* Beff = (u16*)(ws + 256);                 // 4096*6144*2  = 50,331,648
  u16* B2eff = (u16*)(ws + 256 + 50331648);     // 1024*3072*2  =  6,291,456
  u16* Aeff = (u16*)(ws + 256 + 56623104);      // 256*6144*2   =  3,145,728
  float* cbuf = (float*)(ws + 256 + 59768832);  // 256*1024*4   =  1,048,576
  float* gates = (float*)(ws + 256 + 60817408); // 2*256*4096*4 =  8,388,608
  float* ybuf = (float*)(ws + 256 + 69206016);  // 8*256*1024*4 =  8,388,608

  init_bar<<<1, 1, 0, stream>>>(bar);
  prep_w1<<<12288, 256, 0, stream>>>(W_ih, W_hh, Beff);
  prep_w2<<<1536, 256, 0, stream>>>(W_lin, B2eff);
  prep_state<<<768, 256, 0, stream>>>(inputs, h0, c0, Aeff, cbuf);

  fused_persistent<<<NBLK, 256, 0, stream>>>(
      b_ih, b_hh, b_lin, Aeff, Beff, B2eff, cbuf, gates, ybuf, out, bar);
}

// Round 3
// 3816.190 us; speedup vs baseline: 6.9134x; 6.9134x over previous
//
#include <hip/hip_runtime.h>

typedef unsigned short u16;
typedef short bf16x8 __attribute__((ext_vector_type(8)));
typedef float f32x4 __attribute__((ext_vector_type(4)));

#define SLAB (256 * 2048)  // one h-history slab (elems)

__device__ inline u16 f2bf(float f) {
  unsigned u = __float_as_uint(f);
  return (u16)((u + 0x7fffu + ((u >> 16) & 1u)) >> 16);
}
__device__ inline float bf2f(u16 h) { return __uint_as_float(((unsigned)h) << 16); }
__device__ inline float sigf(float x) { return 1.f / (1.f + expf(-x)); }
// interleaved weight-row R -> original gate-major row
__device__ inline int origR(int R) { return ((R >> 4) & 3) * 1024 + (R >> 6) * 16 + (R & 15); }

__device__ inline void gload_lds16(const u16* g, u16* l) {
  __builtin_amdgcn_global_load_lds(
      (const __attribute__((address_space(1))) void*)g,
      (__attribute__((address_space(3))) void*)l, 16, 0, 0);
}

// logical-K-block -> physical-K-block maps (1024-elem blocks).
// MODE 0: A [hi|lo] -> logical [hi|lo|hi]; B [hi|lo] -> logical [hi|hi|lo].
// MODE 1 (step0): A [xhi|xlo|hhi|hlo] -> [xhi|xlo|xhi|hhi|hlo|hhi];
//                 B [Whi|Wlo|Vhi|Vlo] -> [Whi|Whi|Wlo|Vhi|Vhi|Vlo].
template <int MODE>
__device__ __forceinline__ void kmaps(int blk, int& ka, int& kb) {
  if constexpr (MODE == 0) {
    constexpr int KA[3] = {0, 1, 0}, KB[3] = {0, 0, 1};
    ka = KA[blk]; kb = KB[blk];
  } else {
    constexpr int KA[6] = {0, 1, 0, 2, 3, 2}, KB[6] = {0, 0, 1, 2, 2, 3};
    ka = KA[blk]; kb = KB[blk];
  }
}

// C[m][n] = sum_k A[m][klog] * B[n][klog] over logical K = NT*64.
// BM=128, BN=64, BK=64, 256 threads, 4 waves 2x2 (wave tile 64x32).
// LDS tile rows 128B; XOR swizzle (16B unit ^= row&7) baked into the
// global_load_lds SOURCE address (linear LDS dest) and ds_read addresses.
// EPI: 0 = f32 store (pitch 1024), 1 = fused LSTM cell, 2 = y + b_lin store.
template <int NT, int MODE, int MB, int AP, int BP, int EPI, int SWZ>
__global__ __launch_bounds__(256) void gemmk(
    const u16* __restrict__ A, const u16* __restrict__ B,
    const float* __restrict__ bias, float* __restrict__ cbuf,
    u16* __restrict__ hsout, float* __restrict__ fout) {
  __shared__ union {
    u16 ts[4 * 12288];     // 4 bufs x (192 rows x 64 k) = 96 KB
    float g[128 * 65];     // epilogue gate-exchange (aliases bufs 0-1)
  } smem;

  const int bid = blockIdx.x, tid = threadIdx.x;
  int mb, nb;
  if constexpr (SWZ) {  // XCD-aware: each XCD owns 8 consecutive nb (both mb)
    int x = bid & 7, i = bid >> 3;
    nb = x * 8 + (i >> 1);
    mb = i & 1;
  } else {
    mb = bid % MB;
    nb = bid / MB;
  }

  const int lane = tid & 63;
  const int wid = tid >> 6;
  const int wrow = (wid >> 1) * 64;
  const int wcol = (wid & 1) * 32;
  const int lr = lane & 15;
  const int kq = lane >> 4;

  const u16* Ab = A + (size_t)(mb * 128) * AP;
  const u16* Bb = B + (size_t)(nb * 64) * BP;

  // per-thread staging units: 6 x 16B; u<4 => A rows 0..127, u>=4 => B rows.
  const u16* uptr[6];
  int ldsoff[6];
#pragma unroll
  for (int u = 0; u < 6; u++) {
    int ui = u * 256 + tid;
    int r = ui >> 3, j = ui & 7;
    int jp = j ^ (r & 7);  // pre-swizzled source unit
    uptr[u] = (u < 4 ? Ab + r * AP : Bb + (r - 128) * BP) + jp * 8;
    ldsoff[u] = ui * 8;    // linear LDS dest (elems)
  }

  f32x4 acc[4][2];
#pragma unroll
  for (int m = 0; m < 4; m++)
#pragma unroll
    for (int n = 0; n < 2; n++) acc[m][n] = (f32x4)0.f;

  auto STAGE = [&](int buf, int kt) {
    int ka, kb2;
    kmaps<MODE>(kt >> 4, ka, kb2);
    int koA = ka * 1024 + (kt & 15) * 64;
    int koB = kb2 * 1024 + (kt & 15) * 64;
    u16* lb = &smem.ts[buf * 12288];
#pragma unroll
    for (int u = 0; u < 6; u++)
      gload_lds16(uptr[u] + (u < 4 ? koA : koB), lb + ldsoff[u]);
  };

  auto COMPUTE = [&](int cur) {
    const char* base = (const char*)&smem.ts[cur * 12288];
    bf16x8 af[4][2], bv[2][2];
#pragma unroll
    for (int m = 0; m < 4; m++)
#pragma unroll
      for (int kh = 0; kh < 2; kh++) {
        int row = wrow + m * 16 + lr;
        int sw = (kh * 4 + kq) ^ (row & 7);
        af[m][kh] = *(const bf16x8*)(base + row * 128 + sw * 16);
      }
#pragma unroll
    for (int n = 0; n < 2; n++)
#pragma unroll
      for (int kh = 0; kh < 2; kh++) {
        int row = 128 + wcol + n * 16 + lr;
        int sw = (kh * 4 + kq) ^ (row & 7);
        bv[n][kh] = *(const bf16x8*)(base + row * 128 + sw * 16);
      }
#pragma unroll
    for (int kh = 0; kh < 2; kh++)
#pragma unroll
      for (int m = 0; m < 4; m++)
#pragma unroll
        for (int n = 0; n < 2; n++)
          acc[m][n] = __builtin_amdgcn_mfma_f32_16x16x32_bf16(af[m][kh], bv[n][kh], acc[m][n], 0, 0, 0);
  };

  // 4-buffer, depth-2 prefetch. 6 loads/thread/stage -> steady vmcnt(12).
  STAGE(0, 0);
  STAGE(1, 1);
  for (int t = 0; t < NT - 2; t++) {
    STAGE((t + 2) & 3, t + 2);
    asm volatile("s_waitcnt vmcnt(12)" ::: "memory");
    __builtin_amdgcn_s_barrier();
    COMPUTE(t & 3);
  }
  asm volatile("s_waitcnt vmcnt(6)" ::: "memory");
  __builtin_amdgcn_s_barrier();
  COMPUTE((NT - 2) & 3);
  asm volatile("s_waitcnt vmcnt(0)" ::: "memory");
  __builtin_amdgcn_s_barrier();
  COMPUTE((NT - 1) & 3);

  if constexpr (EPI == 0) {
    float* Cb = fout + (size_t)(mb * 128 + wrow) * 1024 + nb * 64 + wcol;
#pragma unroll
    for (int m = 0; m < 4; m++)
#pragma unroll
      for (int n = 0; n < 2; n++)
#pragma unroll
        for (int j = 0; j < 4; j++)
          Cb[(m * 16 + kq * 4 + j) * 1024 + n * 16 + lr] = acc[m][n][j];
  } else if constexpr (EPI == 2) {
    float* Cb = fout + (size_t)(mb * 128 + wrow) * 1024 + nb * 64 + wcol;
#pragma unroll
    for (int n = 0; n < 2; n++) {
      float bl = bias[nb * 64 + wcol + n * 16 + lr];
#pragma unroll
      for (int m = 0; m < 4; m++)
#pragma unroll
        for (int j = 0; j < 4; j++)
          Cb[(m * 16 + kq * 4 + j) * 1024 + n * 16 + lr] = acc[m][n][j] + bl;
    }
  } else {
    // fused LSTM cell: exchange gates via LDS (cols: [i|f|g|o] x 16 n each)
    __syncthreads();  // all COMPUTE reads done; bufs 0-1 reusable
#pragma unroll
    for (int m = 0; m < 4; m++)
#pragma unroll
      for (int n = 0; n < 2; n++)
#pragma unroll
        for (int j = 0; j < 4; j++)
          smem.g[(wrow + m * 16 + kq * 4 + j) * 65 + wcol + n * 16 + lr] = acc[m][n][j];
    __syncthreads();
    const int nn = tid & 15;
    const int rb0 = tid >> 4;
    const float bi = bias[nb * 64 + nn];
    const float bf = bias[nb * 64 + 16 + nn];
    const float bg = bias[nb * 64 + 32 + nn];
    const float bo = bias[nb * 64 + 48 + nn];
#pragma unroll
    for (int i = 0; i < 8; i++) {
      int r = rb0 + i * 16;
      float xi = smem.g[r * 65 + nn] + bi;
      float xf = smem.g[r * 65 + 16 + nn] + bf;
      float xg = smem.g[r * 65 + 32 + nn] + bg;
      float xo = smem.g[r * 65 + 48 + nn] + bo;
      int b = mb * 128 + r;
      int cidx = b * 1024 + nb * 16 + nn;
      float cn = sigf(xf) * cbuf[cidx] + sigf(xi) * tanhf(xg);
      float h = sigf(xo) * tanhf(cn);
      cbuf[cidx] = cn;
      u16 hi = f2bf(h);
      u16 lo = f2bf(h - bf2f(hi));
      hsout[b * 2048 + nb * 16 + nn] = hi;
      hsout[b * 2048 + 1024 + nb * 16 + nn] = lo;
    }
  }
}

// ---- prep kernels ----

// Wih_eff[R][hi|lo] from W_ih[origR(R)]
__global__ __launch_bounds__(256) void prep_wih(const float* __restrict__ W,
                                                u16* __restrict__ out) {
  int i = blockIdx.x * 256 + threadIdx.x;  // 4096 rows x 256 units
  int r = i >> 8, u = i & 255, half = u >> 7, k8 = (u & 127) << 3;
  const float* s = W + origR(r) * 1024 + k8;
  u16* o = out + r * 2048 + half * 1024 + k8;
#pragma unroll
  for (int e = 0; e < 8; e++) {
    float f = s[e];
    u16 hi = f2bf(f);
    o[e] = half ? f2bf(f - bf2f(hi)) : hi;
  }
}

// Wlt_eff[k][hi(j)|lo(j)] from W_lin[j][k] (transpose)
__global__ __launch_bounds__(256) void prep_wlt(const float* __restrict__ W,
                                                u16* __restrict__ out) {
  int i = blockIdx.x * 256 + threadIdx.x;  // 1024 rows x 256 units
  int k = i >> 8, u = i & 255, half = u >> 7, j8 = (u & 127) << 3;
  u16* o = out + k * 2048 + half * 1024 + j8;
#pragma unroll
  for (int e = 0; e < 8; e++) {
    float f = W[(j8 + e) * 1024 + k];
    u16 hi = f2bf(f);
    o[e] = half ? f2bf(f - bf2f(hi)) : hi;
  }
}

// Wlin_eff[j][hi|lo] from W_lin[j][k] (no transpose)
__global__ __launch_bounds__(256) void prep_wlin(const float* __restrict__ W,
                                                 u16* __restrict__ out) {
  int i = blockIdx.x * 256 + threadIdx.x;
  int j = i >> 8, u = i & 255, half = u >> 7, k8 = (u & 127) << 3;
  const float* s = W + j * 1024 + k8;
  u16* o = out + j * 2048 + half * 1024 + k8;
#pragma unroll
  for (int e = 0; e < 8; e++) {
    float f = s[e];
    u16 hi = f2bf(f);
    o[e] = half ? f2bf(f - bf2f(hi)) : hi;
  }
}

// Beff[R][hi|lo] = split(Wc_f32[R] + W_hh[origR(R)])
__global__ __launch_bounds__(256) void prep_beff(const float* __restrict__ Wc,
                                                 const float* __restrict__ Whh,
                                                 u16* __restrict__ out) {
  int i = blockIdx.x * 256 + threadIdx.x;
  int r = i >> 8, u = i & 255, half = u >> 7, k8 = (u & 127) << 3;
  const float* s1 = Wc + r * 1024 + k8;
  const float* s2 = Whh + origR(r) * 1024 + k8;
  u16* o = out + r * 2048 + half * 1024 + k8;
#pragma unroll
  for (int e = 0; e < 8; e++) {
    float f = s1[e] + s2[e];
    u16 hi = f2bf(f);
    o[e] = half ? f2bf(f - bf2f(hi)) : hi;
  }
}

// B0eff[R] = [Wih_hi|Wih_lo|Whh_hi|Whh_lo] of origR(R)
__global__ __launch_bounds__(256) void prep_b0(const float* __restrict__ Wih,
                                               const float* __restrict__ Whh,
                                               u16* __restrict__ out) {
  int i = blockIdx.x * 256 + threadIdx.x;  // 4096 rows x 512 units
  int r = i >> 9, u = i & 511, quad = u >> 7, k8 = (u & 127) << 3;
  const float* s = (quad < 2 ? Wih : Whh) + origR(r) * 1024 + k8;
  bool lo = quad & 1;
  u16* o = out + (size_t)r * 4096 + quad * 1024 + k8;
#pragma unroll
  for (int e = 0; e < 8; e++) {
    float f = s[e];
    u16 hi = f2bf(f);
    o[e] = lo ? f2bf(f - bf2f(hi)) : hi;
  }
}

// A0eff[b] = [x_hi|x_lo|h_hi|h_lo]; also cbuf <- c0
__global__ __launch_bounds__(256) void prep_a0(const float* __restrict__ x0,
                                               const float* __restrict__ h0,
                                               const float* __restrict__ c0,
                                               u16* __restrict__ out,
                                               float* __restrict__ cbuf) {
  int i = blockIdx.x * 256 + threadIdx.x;  // 256 rows x 512 units
  int b = i >> 9, u = i & 511, quad = u >> 7, k8 = (u & 127) << 3;
  const float* s = (quad < 2 ? x0 : h0) + b * 1024 + k8;
  bool lo = quad & 1;
  u16* o = out + b * 4096 + quad * 1024 + k8;
#pragma unroll
  for (int e = 0; e < 8; e++) {
    float f = s[e];
    u16 hi = f2bf(f);
    o[e] = lo ? f2bf(f - bf2f(hi)) : hi;
  }
  if (i < 32768) {
    float4 v0 = *(const float4*)&c0[i * 8];
    float4 v1 = *(const float4*)&c0[i * 8 + 4];
    *(float4*)&cbuf[i * 8] = v0;
    *(float4*)&cbuf[i * 8 + 4] = v1;
  }
}

// bc0[R] = b_ih[o]+b_hh[o]; bc1[R] = bc0[R] + dot(W_ih[o,:], b_lin)
__global__ __launch_bounds__(256) void prep_bias(const float* __restrict__ Wih,
                                                 const float* __restrict__ b_ih,
                                                 const float* __restrict__ b_hh,
                                                 const float* __restrict__ b_lin,
                                                 float* __restrict__ bc0,
                                                 float* __restrict__ bc1) {
  int wid = threadIdx.x >> 6, lane = threadIdx.x & 63;
  int R = blockIdx.x * 4 + wid;
  int o = origR(R);
  float p = 0.f;
#pragma unroll
  for (int it = 0; it < 16; it++) {
    int j = lane + it * 64;
    p += Wih[o * 1024 + j] * b_lin[j];
  }
#pragma unroll
  for (int m = 1; m < 64; m <<= 1) p += __shfl_xor(p, m);
  if (lane == 0) {
    float s = b_ih[o] + b_hh[o];
    bc0[R] = s;
    bc1[R] = s + p;
  }
}

// In-place BatchNorm over batch axis (proven in R1)
__global__ __launch_bounds__(256) void bn_kernel(float* __restrict__ out) {
  int t = blockIdx.x >> 2;
  int d = ((blockIdx.x & 3) << 8) + threadIdx.x;
  float* base = out + (size_t)t * (256 * 1024) + d;
  float s = 0.f;
  for (int b = 0; b < 256; b++) s += base[b * 1024];
  float mean = s * (1.f / 256.f);
  float vs = 0.f;
  for (int b = 0; b < 256; b++) {
    float x = base[b * 1024] - mean;
    vs += x * x;
  }
  float rstd = rsqrtf(vs * (1.f / 256.f) + 1e-5f);
  for (int b = 0; b < 256; b++) base[b * 1024] = (base[b * 1024] - mean) * rstd;
}

extern "C" void kernel_launch(void* const* d_in, const int* in_sizes, int n_in,
                              void* d_out, int out_size, void* d_ws, size_t ws_size,
                              hipStream_t stream) {
  const float* inputs = (const float*)d_in[0];
  const float* W_ih = (const float*)d_in[1];
  const float* W_hh = (const float*)d_in[2];
  const float* b_ih = (const float*)d_in[3];
  const float* b_hh = (const float*)d_in[4];
  const float* W_lin = (const float*)d_in[5];
  const float* b_lin = (const float*)d_in[6];
  const float* h0 = (const float*)d_in[7];
  const float* c0 = (const float*)d_in[8];
  float* out = (float*)d_out;

  char* ws = (char*)d_ws;
  float* bc0 = (float*)ws;                         //     16,384
  float* bc1 = (float*)(ws + 16384);               //     16,384
  u16* Wlin_eff = (u16*)(ws + 32768);              //  4,194,304
  u16* Beff = (u16*)(ws + 4227072);                // 16,777,216
  u16* B0eff = (u16*)(ws + 21004288);              // 33,554,432
  u16* A0eff = (u16*)(ws + 54558720);              //  2,097,152
  float* cbuf = (float*)(ws + 56655872);           //  1,048,576
  u16* Hs = (u16*)(ws + 57704448);                 // 134,217,728 (128 slabs)
  // prep transients alias the Hs region (dead before step kernels run):
  u16* Wih_eff = (u16*)(ws + 57704448);            // 16,777,216
  u16* Wlt_eff = (u16*)(ws + 57704448 + 16777216); //  4,194,304
  float* Wc_f32 = (float*)(ws + 57704448 + 20971520); // 16,777,216

  prep_wih<<<4096, 256, 0, stream>>>(W_ih, Wih_eff);
  prep_wlt<<<1024, 256, 0, stream>>>(W_lin, Wlt_eff);
  prep_wlin<<<1024, 256, 0, stream>>>(W_lin, Wlin_eff);
  prep_b0<<<8192, 256, 0, stream>>>(W_ih, W_hh, B0eff);
  prep_a0<<<512, 256, 0, stream>>>(inputs, h0, c0, A0eff, cbuf);
  prep_bias<<<1024, 256, 0, stream>>>(W_ih, b_ih, b_hh, b_lin, bc0, bc1);

  // W_c = W_ih @ W_lin (bf16x3), rows in interleaved order
  gemmk<48, 0, 32, 2048, 2048, 0, 0><<<512, 256, 0, stream>>>(
      Wih_eff, Wlt_eff, nullptr, nullptr, nullptr, Wc_f32);
  prep_beff<<<4096, 256, 0, stream>>>(Wc_f32, W_hh, Beff);

  // step 0: gates from (x0, h0), K_log = 6144
  gemmk<96, 1, 2, 4096, 4096, 1, 1><<<128, 256, 0, stream>>>(
      A0eff, B0eff, bc0, cbuf, Hs, nullptr);
  // steps 1..127: gates from h only, K_log = 3072
  for (int t = 1; t < 128; t++) {
    gemmk<48, 0, 2, 2048, 2048, 1, 1><<<128, 256, 0, stream>>>(
        Hs + (size_t)(t - 1) * SLAB, Beff, bc1, cbuf, Hs + (size_t)t * SLAB, nullptr);
  }

  // ys = Hs @ W_lin^T + b_lin  (M = 32768)
  gemmk<48, 0, 256, 2048, 2048, 2, 0><<<4096, 256, 0, stream>>>(
      Hs, Wlin_eff, b_lin, nullptr, nullptr, out);
  bn_kernel<<<512, 256, 0, stream>>>(out);
}